// Round 1
// baseline (726.844 us; speedup 1.0000x reference)
//
#include <hip/hip_runtime.h>

#define H 128          // hidden dim (fixed by problem)
#define CAP 64         // max edges per (rel,dst) bucket; deg ~ Poisson(6), overflow P ~ 1e-40

// ---------------- edge bucketing: one pass, reused by both layers ----------------
__global__ __launch_bounds__(256) void hist_fill(const int* __restrict__ src,
    const int* __restrict__ dst, const int* __restrict__ et,
    int* __restrict__ cnt, int* __restrict__ elist, int E, int N)
{
    int e = blockIdx.x * 256 + threadIdx.x;
    if (e >= E) return;
    int s = src[e], d = dst[e], t = et[e];
    int b = t * N + d;
    int pos = atomicAdd(&cnt[b], 1);
    if (pos < CAP) elist[(size_t)b * CAP + pos] = s;
}

// ---------------- fp32 tiled GEMM: C[M,128] = A[M,K] @ W[K,128] (+bias) (leaky?) ---
// block: 256 threads -> 64 rows x 128 cols tile; thread tile 4x8; K chunked by 32.
__global__ __launch_bounds__(256) void gemm_tiled(const float* __restrict__ A,
    const float* __restrict__ W, const float* __restrict__ bias,
    float* __restrict__ C, int M, int K, int leaky)
{
    __shared__ float As[32][68];   // [k][row], stride 68 keeps 16B align + breaks conflicts
    __shared__ float Bs[32][H];    // [k][col]

    const int tid = threadIdx.x;
    const int bm  = blockIdx.x * 64;
    const int ty  = tid >> 4;      // 0..15 -> rows 4ty..4ty+3
    const int tx  = tid & 15;      // 0..15 -> cols 8tx..8tx+7

    float acc[4][8];
#pragma unroll
    for (int i = 0; i < 4; i++)
#pragma unroll
        for (int j = 0; j < 8; j++) acc[i][j] = 0.0f;

    const int ar = tid >> 3;          // 0..31
    const int ac = (tid & 7) * 4;     // 0,4,...,28
    const int br = tid >> 5;          // 0..7
    const int bc = (tid & 31) * 4;    // 0..124

    for (int k0 = 0; k0 < K; k0 += 32) {
        // stage A tile (64 rows x 32 k), transposed into As[k][row]
#pragma unroll
        for (int p = 0; p < 2; p++) {
            int row = bm + ar + p * 32;
            float4 v = make_float4(0.f, 0.f, 0.f, 0.f);
            if (row < M) v = *(const float4*)&A[(size_t)row * K + k0 + ac];
            As[ac + 0][ar + p * 32] = v.x;
            As[ac + 1][ar + p * 32] = v.y;
            As[ac + 2][ar + p * 32] = v.z;
            As[ac + 3][ar + p * 32] = v.w;
        }
        // stage B tile (32 k x 128 cols)
#pragma unroll
        for (int p = 0; p < 4; p++) {
            *(float4*)&Bs[br + p * 8][bc] =
                *(const float4*)&W[(size_t)(k0 + br + p * 8) * H + bc];
        }
        __syncthreads();

#pragma unroll
        for (int k = 0; k < 32; k++) {
            const float4 av  = *(const float4*)&As[k][ty * 4];
            const float4 bv0 = *(const float4*)&Bs[k][tx * 8];
            const float4 bv1 = *(const float4*)&Bs[k][tx * 8 + 4];
            const float arr[4] = {av.x, av.y, av.z, av.w};
            const float brr[8] = {bv0.x, bv0.y, bv0.z, bv0.w, bv1.x, bv1.y, bv1.z, bv1.w};
#pragma unroll
            for (int i = 0; i < 4; i++)
#pragma unroll
                for (int j = 0; j < 8; j++) acc[i][j] += arr[i] * brr[j];
        }
        __syncthreads();
    }

    // epilogue
    float bia[8];
#pragma unroll
    for (int j = 0; j < 8; j++) bia[j] = bias ? bias[tx * 8 + j] : 0.0f;

#pragma unroll
    for (int i = 0; i < 4; i++) {
        int row = bm + ty * 4 + i;
        if (row >= M) continue;
        float o[8];
#pragma unroll
        for (int j = 0; j < 8; j++) {
            float v = acc[i][j] + bia[j];
            if (leaky) v = (v >= 0.0f) ? v : 0.01f * v;
            o[j] = v;
        }
        *(float4*)&C[(size_t)row * H + tx * 8]     = make_float4(o[0], o[1], o[2], o[3]);
        *(float4*)&C[(size_t)row * H + tx * 8 + 4] = make_float4(o[4], o[5], o[6], o[7]);
    }
}

// ---------------- mean-aggregate gather: y[dst] += sum_r mean(h_r[src]) -----------
// one wave per dst row; wave owns the row -> no atomics.
__global__ __launch_bounds__(256) void gather_mean(float* __restrict__ y,
    const float* __restrict__ h, const int* __restrict__ elist,
    const int* __restrict__ cnt, int N, int R)
{
    int w = blockIdx.x * 4 + (threadIdx.x >> 6);
    int lane = threadIdx.x & 63;
    if (w >= N) return;

    float2 acc = *(const float2*)&y[(size_t)w * H + lane * 2];
    for (int r = 0; r < R; r++) {
        int b = r * N + w;
        int deg = cnt[b];
        if (deg == 0) continue;
        int len = deg < CAP ? deg : CAP;
        const int* lst = &elist[(size_t)b * CAP];
        const float* hr = h + (size_t)r * N * H;
        float sx = 0.f, sy = 0.f;
        for (int i = 0; i < len; i++) {
            int s = lst[i];
            const float2 v = *(const float2*)&hr[(size_t)s * H + lane * 2];
            sx += v.x; sy += v.y;
        }
        float inv = 1.0f / (float)deg;
        acc.x += sx * inv; acc.y += sy * inv;
    }
    *(float2*)&y[(size_t)w * H + lane * 2] = acc;
}

// ---------------- final projection: out[N,OUT] = X[N,128] @ Wo[128,OUT] + bo ------
__global__ __launch_bounds__(256) void out_gemm(const float* __restrict__ X,
    const float* __restrict__ Wo, const float* __restrict__ bo,
    float* __restrict__ out, int N, int OUT)
{
    int row = blockIdx.x * 4 + (threadIdx.x >> 6);
    int lane = threadIdx.x & 63;
    if (row >= N) return;
    float a0 = X[(size_t)row * H + lane];
    float a1 = X[(size_t)row * H + 64 + lane];
    for (int c = 0; c < OUT; c++) {
        float p = a0 * Wo[lane * OUT + c] + a1 * Wo[(64 + lane) * OUT + c];
        for (int off = 32; off > 0; off >>= 1) p += __shfl_down(p, off);
        if (lane == 0) out[(size_t)row * OUT + c] = p + bo[c];
    }
}

extern "C" void kernel_launch(void* const* d_in, const int* in_sizes, int n_in,
                              void* d_out, int out_size, void* d_ws, size_t ws_size,
                              hipStream_t stream) {
    const float* feature = (const float*)d_in[0];
    const int*   ei      = (const int*)d_in[1];   // [2,E]: src then dst
    const int*   et      = (const int*)d_in[2];   // [E]
    const float* w_in    = (const float*)d_in[3];
    const float* b_in    = (const float*)d_in[4];
    const float* w_rel   = (const float*)d_in[5];
    const float* w_root  = (const float*)d_in[6];
    const float* b_conv  = (const float*)d_in[7];
    const float* w_out   = (const float*)d_in[8];
    const float* b_out   = (const float*)d_in[9];

    const int HH   = in_sizes[4];                 // 128
    const int D_IN = in_sizes[3] / HH;            // 768
    const int N    = in_sizes[0] / D_IN;          // 50000
    const int E    = in_sizes[1] / 2;             // 600000
    const int R    = in_sizes[5] / (HH * HH);     // 2
    const int OUT  = in_sizes[9];                 // 3

    // workspace layout
    float* x   = (float*)d_ws;                    // N*H
    float* y   = x + (size_t)N * H;               // N*H
    float* h   = y + (size_t)N * H;               // R*N*H
    int* cnt   = (int*)(h + (size_t)R * N * H);   // R*N
    int* elist = cnt + (size_t)R * N;             // R*N*CAP

    hipMemsetAsync(cnt, 0, sizeof(int) * (size_t)R * N, stream);
    hist_fill<<<(E + 255) / 256, 256, 0, stream>>>(ei, ei + E, et, cnt, elist, E, N);

    const int gblocks = (N + 63) / 64;
    // x = leakyrelu(feature @ w_in + b_in)
    gemm_tiled<<<gblocks, 256, 0, stream>>>(feature, w_in, b_in, x, N, D_IN, 1);

    for (int layer = 0; layer < 2; layer++) {
        gemm_tiled<<<gblocks, 256, 0, stream>>>(x, w_root, b_conv, y, N, HH, 0);
        for (int r = 0; r < R; r++)
            gemm_tiled<<<gblocks, 256, 0, stream>>>(x, w_rel + (size_t)r * HH * HH,
                                                    nullptr, h + (size_t)r * N * H, N, HH, 0);
        gather_mean<<<(N + 3) / 4, 256, 0, stream>>>(y, h, elist, cnt, N, R);
        float* t = x; x = y; y = t;
    }

    out_gemm<<<(N + 3) / 4, 256, 0, stream>>>(x, w_out, b_out, (float*)d_out, N, OUT);
}

// Round 2
// 532.027 us; speedup vs baseline: 1.3662x; 1.3662x over previous
//
#include <hip/hip_runtime.h>

#define H 128          // hidden dim (fixed by problem)
#define CAP 64         // max edges per (rel,dst) bucket

typedef _Float16 f16x8 __attribute__((ext_vector_type(8)));
typedef float    f32x4 __attribute__((ext_vector_type(4)));

// ---------------- edge bucketing: one pass, reused by both layers ----------------
__global__ __launch_bounds__(256) void hist_fill(const int* __restrict__ src,
    const int* __restrict__ dst, const int* __restrict__ et,
    int* __restrict__ cnt, int* __restrict__ elist, int E, int N)
{
    int e = blockIdx.x * 256 + threadIdx.x;
    if (e >= E) return;
    int s = src[e], d = dst[e], t = et[e];
    int b = t * N + d;
    int pos = atomicAdd(&cnt[b], 1);
    if (pos < CAP) elist[(size_t)b * CAP + pos] = s;
}

// ---------------- weight prep: transpose + fp32->fp16 ----------------
// wInT[c][k] = w_in[k][c]  (128 x K)
// w3T[m][c][k]: m=0 w_root, m=1 w_rel0, m=2 w_rel1  (each 128 x 128)
__global__ __launch_bounds__(256) void prep_w(const float* __restrict__ w_in,
    const float* __restrict__ w_root, const float* __restrict__ w_rel,
    _Float16* __restrict__ wInT, _Float16* __restrict__ w3T, int K)
{
    int idx = blockIdx.x * 256 + threadIdx.x;
    int tot1 = K * H;
    if (idx < tot1) {
        int c = idx / K, k = idx - c * K;
        wInT[idx] = (_Float16)w_in[(size_t)k * H + c];
    } else {
        int i2 = idx - tot1;
        if (i2 < 3 * H * H) {
            int m = i2 / (H * H), r2 = i2 - m * (H * H);
            int c = r2 >> 7, k = r2 & 127;
            const float* s = (m == 0) ? w_root : (w_rel + (size_t)(m - 1) * H * H);
            w3T[i2] = (_Float16)s[(size_t)k * H + c];
        }
    }
}

// ---------------- big MFMA GEMM: C = leakyrelu(A[M,K] @ W[K,128] + b) ------------
// A fp32, W pre-transposed fp16 [128][K]. Tile 128x128, BK=32, 4 waves, 4x4 tiles/wave.
__global__ __launch_bounds__(256) void gemm_big(const float* __restrict__ A,
    const _Float16* __restrict__ WT, const float* __restrict__ bias,
    float* __restrict__ C, int M, int K)
{
    __shared__ _Float16 Xs[128][40];   // [row][k], stride 40 (80B: 2-way conflicts only)
    __shared__ _Float16 Ws[128][40];   // [col][k]

    const int tid = threadIdx.x;
    const int bm  = blockIdx.x * 128;
    const int w   = tid >> 6;
    const int l   = tid & 63;
    const int l15 = l & 15;
    const int q   = l >> 4;
    const int wr  = (w & 1) * 64;
    const int wc  = (w >> 1) * 64;

    f32x4 acc[4][4];
    const f32x4 z4 = {0.f, 0.f, 0.f, 0.f};
#pragma unroll
    for (int i = 0; i < 4; i++)
#pragma unroll
        for (int j = 0; j < 4; j++) acc[i][j] = z4;

    const int sr = tid >> 1;          // 0..127: stage row (A) / col (W)
    const int sk = (tid & 1) * 16;    // 0 or 16

    for (int k0 = 0; k0 < K; k0 += 32) {
        // stage A (fp32 -> fp16)
        {
            const float* ap = A + (size_t)(bm + sr) * K + k0 + sk;
            bool ok = (bm + sr) < M;
            float va[16];
#pragma unroll
            for (int ii = 0; ii < 4; ii++) {
                float4 v = ok ? *(const float4*)(ap + 4 * ii) : make_float4(0.f, 0.f, 0.f, 0.f);
                va[4 * ii + 0] = v.x; va[4 * ii + 1] = v.y;
                va[4 * ii + 2] = v.z; va[4 * ii + 3] = v.w;
            }
            f16x8 h0, h1;
#pragma unroll
            for (int jj = 0; jj < 8; jj++) { h0[jj] = (_Float16)va[jj]; h1[jj] = (_Float16)va[8 + jj]; }
            *(f16x8*)&Xs[sr][sk]     = h0;
            *(f16x8*)&Xs[sr][sk + 8] = h1;
        }
        // stage W (already fp16, contiguous k)
        {
            const _Float16* wp = WT + (size_t)sr * K + k0 + sk;
            *(f16x8*)&Ws[sr][sk]     = *(const f16x8*)(wp);
            *(f16x8*)&Ws[sr][sk + 8] = *(const f16x8*)(wp + 8);
        }
        __syncthreads();

        f16x8 af[4], bf[4];
#pragma unroll
        for (int i = 0; i < 4; i++) af[i] = *(const f16x8*)&Xs[wr + i * 16 + l15][q * 8];
#pragma unroll
        for (int j = 0; j < 4; j++) bf[j] = *(const f16x8*)&Ws[wc + j * 16 + l15][q * 8];
#pragma unroll
        for (int i = 0; i < 4; i++)
#pragma unroll
            for (int j = 0; j < 4; j++)
                acc[i][j] = __builtin_amdgcn_mfma_f32_16x16x32_f16(af[i], bf[j], acc[i][j], 0, 0, 0);
        __syncthreads();
    }

    // epilogue: bias + leaky, fp32 store
#pragma unroll
    for (int j = 0; j < 4; j++) {
        int col = wc + j * 16 + l15;
        float bj = bias[col];
#pragma unroll
        for (int i = 0; i < 4; i++)
#pragma unroll
            for (int rg = 0; rg < 4; rg++) {
                int row = bm + wr + i * 16 + q * 4 + rg;
                if (row < M) {
                    float v = acc[i][j][rg] + bj;
                    v = (v >= 0.f) ? v : 0.01f * v;
                    C[(size_t)row * H + col] = v;
                }
            }
    }
}

// ---------------- fused per-layer GEMM: y = x@w_root+b; h_r = x@w_rel[r] ---------
// Stages x-tile once (fp16, XOR-swizzled), loops 3 weights. LDS = 64 KB exactly.
__device__ __forceinline__ int sw(int r, int kf16) {
    return r * 128 + ((((kf16) >> 3) ^ (r & 15)) << 3);   // 16B-chunk XOR swizzle
}

__global__ __launch_bounds__(256) void gemm3(const float* __restrict__ X,
    const _Float16* __restrict__ W3, const float* __restrict__ bias,
    float* __restrict__ Y, float* __restrict__ Hh, int M)
{
    __shared__ _Float16 Xs[128 * 128];
    __shared__ _Float16 Ws[128 * 128];

    const int tid = threadIdx.x;
    const int bm  = blockIdx.x * 128;
    const int w   = tid >> 6;
    const int l   = tid & 63;
    const int l15 = l & 15;
    const int q   = l >> 4;
    const int wr  = (w & 1) * 64;
    const int wc  = (w >> 1) * 64;

    const int sr = tid >> 1;
    const int sk = (tid & 1) * 64;

    // stage x-tile (fp32 -> fp16)
    {
        const float* xp = X + (size_t)(bm + sr) * H + sk;
        bool ok = (bm + sr) < M;
#pragma unroll
        for (int ii = 0; ii < 8; ii++) {
            float4 v0 = ok ? *(const float4*)(xp + 8 * ii)     : make_float4(0.f, 0.f, 0.f, 0.f);
            float4 v1 = ok ? *(const float4*)(xp + 8 * ii + 4) : make_float4(0.f, 0.f, 0.f, 0.f);
            f16x8 hv;
            hv[0] = (_Float16)v0.x; hv[1] = (_Float16)v0.y; hv[2] = (_Float16)v0.z; hv[3] = (_Float16)v0.w;
            hv[4] = (_Float16)v1.x; hv[5] = (_Float16)v1.y; hv[6] = (_Float16)v1.z; hv[7] = (_Float16)v1.w;
            *(f16x8*)&Xs[sw(sr, sk + 8 * ii)] = hv;
        }
    }

    const f32x4 z4 = {0.f, 0.f, 0.f, 0.f};

    for (int m = 0; m < 3; m++) {
        if (m) __syncthreads();   // previous compute's LDS reads done before overwrite
        {
            const _Float16* wp = W3 + (size_t)m * H * H + (size_t)sr * H + sk;
#pragma unroll
            for (int ii = 0; ii < 8; ii++)
                *(f16x8*)&Ws[sw(sr, sk + 8 * ii)] = *(const f16x8*)(wp + 8 * ii);
        }
        __syncthreads();

        f32x4 acc[4][4];
#pragma unroll
        for (int i = 0; i < 4; i++)
#pragma unroll
            for (int j = 0; j < 4; j++) acc[i][j] = z4;

#pragma unroll
        for (int kk = 0; kk < 4; kk++) {
            f16x8 af[4], bf[4];
#pragma unroll
            for (int i = 0; i < 4; i++) af[i] = *(const f16x8*)&Xs[sw(wr + i * 16 + l15, kk * 32 + q * 8)];
#pragma unroll
            for (int j = 0; j < 4; j++) bf[j] = *(const f16x8*)&Ws[sw(wc + j * 16 + l15, kk * 32 + q * 8)];
#pragma unroll
            for (int i = 0; i < 4; i++)
#pragma unroll
                for (int j = 0; j < 4; j++)
                    acc[i][j] = __builtin_amdgcn_mfma_f32_16x16x32_f16(af[i], bf[j], acc[i][j], 0, 0, 0);
        }

        float* OUT = (m == 0) ? Y : (Hh + (size_t)(m - 1) * M * H);
#pragma unroll
        for (int j = 0; j < 4; j++) {
            int col = wc + j * 16 + l15;
            float bj = (m == 0) ? bias[col] : 0.f;
#pragma unroll
            for (int i = 0; i < 4; i++)
#pragma unroll
                for (int rg = 0; rg < 4; rg++) {
                    int row = bm + wr + i * 16 + q * 4 + rg;
                    if (row < M) OUT[(size_t)row * H + col] = acc[i][j][rg] + bj;
                }
        }
    }
}

// ---------------- mean-aggregate gather: y[dst] += sum_r mean(h_r[src]) -----------
__global__ __launch_bounds__(256) void gather_mean(float* __restrict__ y,
    const float* __restrict__ h, const int* __restrict__ elist,
    const int* __restrict__ cnt, int N, int R)
{
    int w = blockIdx.x * 4 + (threadIdx.x >> 6);
    int lane = threadIdx.x & 63;
    if (w >= N) return;

    float2 acc = *(const float2*)&y[(size_t)w * H + lane * 2];
    for (int r = 0; r < R; r++) {
        int b = r * N + w;
        int deg = cnt[b];
        if (deg == 0) continue;
        int len = deg < CAP ? deg : CAP;
        const int* lst = &elist[(size_t)b * CAP];
        const float* hr = h + (size_t)r * N * H;
        float sx = 0.f, sy = 0.f;
        for (int i = 0; i < len; i++) {
            int s = lst[i];
            const float2 v = *(const float2*)&hr[(size_t)s * H + lane * 2];
            sx += v.x; sy += v.y;
        }
        float inv = 1.0f / (float)deg;
        acc.x += sx * inv; acc.y += sy * inv;
    }
    *(float2*)&y[(size_t)w * H + lane * 2] = acc;
}

// ---------------- final projection: out[N,OUT] = X[N,128] @ Wo[128,OUT] + bo ------
__global__ __launch_bounds__(256) void out_gemm(const float* __restrict__ X,
    const float* __restrict__ Wo, const float* __restrict__ bo,
    float* __restrict__ out, int N, int OUT)
{
    int row = blockIdx.x * 4 + (threadIdx.x >> 6);
    int lane = threadIdx.x & 63;
    if (row >= N) return;
    float a0 = X[(size_t)row * H + lane];
    float a1 = X[(size_t)row * H + 64 + lane];
    for (int c = 0; c < OUT; c++) {
        float p = a0 * Wo[lane * OUT + c] + a1 * Wo[(64 + lane) * OUT + c];
        for (int off = 32; off > 0; off >>= 1) p += __shfl_down(p, off);
        if (lane == 0) out[(size_t)row * OUT + c] = p + bo[c];
    }
}

extern "C" void kernel_launch(void* const* d_in, const int* in_sizes, int n_in,
                              void* d_out, int out_size, void* d_ws, size_t ws_size,
                              hipStream_t stream) {
    const float* feature = (const float*)d_in[0];
    const int*   ei      = (const int*)d_in[1];   // [2,E]: src then dst
    const int*   et      = (const int*)d_in[2];   // [E]
    const float* w_in    = (const float*)d_in[3];
    const float* b_in    = (const float*)d_in[4];
    const float* w_rel   = (const float*)d_in[5];
    const float* w_root  = (const float*)d_in[6];
    const float* b_conv  = (const float*)d_in[7];
    const float* w_out   = (const float*)d_in[8];
    const float* b_out   = (const float*)d_in[9];

    const int HH   = in_sizes[4];                 // 128
    const int D_IN = in_sizes[3] / HH;            // 768
    const int N    = in_sizes[0] / D_IN;          // 50000
    const int E    = in_sizes[1] / 2;             // 600000
    const int R    = in_sizes[5] / (HH * HH);     // 2
    const int OUT  = in_sizes[9];                 // 3

    // workspace layout (16B-aligned segments)
    char* base = (char*)d_ws;
    _Float16* wInT = (_Float16*)base;                       // 128*768
    _Float16* w3T  = (_Float16*)(base + (size_t)D_IN * HH * 2);
    float* x   = (float*)(base + (size_t)D_IN * HH * 2 + (size_t)3 * HH * HH * 2);
    float* y   = x + (size_t)N * H;
    float* h   = y + (size_t)N * H;               // R*N*H
    int* cnt   = (int*)(h + (size_t)R * N * H);   // R*N
    int* elist = cnt + (size_t)R * N;             // R*N*CAP

    hipMemsetAsync(cnt, 0, sizeof(int) * (size_t)R * N, stream);
    prep_w<<<(D_IN * HH + 3 * HH * HH + 255) / 256, 256, 0, stream>>>(
        w_in, w_root, w_rel, wInT, w3T, D_IN);
    hist_fill<<<(E + 255) / 256, 256, 0, stream>>>(ei, ei + E, et, cnt, elist, E, N);

    const int gblocks = (N + 127) / 128;
    // x = leakyrelu(feature @ w_in + b_in)
    gemm_big<<<gblocks, 256, 0, stream>>>(feature, wInT, b_in, x, N, D_IN);

    for (int layer = 0; layer < 2; layer++) {
        gemm3<<<gblocks, 256, 0, stream>>>(x, w3T, b_conv, y, h, N);
        gather_mean<<<(N + 3) / 4, 256, 0, stream>>>(y, h, elist, cnt, N, R);
        float* t = x; x = y; y = t;
    }

    out_gemm<<<(N + 3) / 4, 256, 0, stream>>>(x, w_out, b_out, (float*)d_out, N, OUT);
}